// Round 2
// baseline (193.692 us; speedup 1.0000x reference)
//
#include <hip/hip_runtime.h>

// Problem constants (from reference)
#define D0 256
#define D1 256
#define D2 256
#define NPTS 65536
#define WIN 7
#define HALF 3
#define OFFS_PER_PT (WIN * WIN * WIN)   // 343
#define TOTAL_PAIRS (NPTS * OFFS_PER_PT)

__global__ __launch_bounds__(256)
void splat_kernel(const float* __restrict__ paras,
                  const float* __restrict__ dist_p,
                  const float* __restrict__ thr_p,
                  float* __restrict__ out) {
    int tid = blockIdx.x * blockDim.x + threadIdx.x;
    if (tid >= TOTAL_PAIRS) return;

    int p = tid / OFFS_PER_PT;          // point index
    int o = tid - p * OFFS_PER_PT;      // offset index 0..342
    int oi = o / 49;
    int rem = o - oi * 49;
    int oj = rem / 7;
    int ok = rem - oj * 7;

    const int N = NPTS;
    // paras layout: rows [px,py,pz, val, rx,rxy,rxz, ry,ryz, rz] x N
    float px = paras[0 * N + p];
    float py = paras[1 * N + p];
    float pz = paras[2 * N + p];

    int cx = (int)floorf(px) - HALF;
    int cy = (int)floorf(py) - HALF;
    int cz = (int)floorf(pz) - HALF;

    int vx = cx + oi;
    int vy = cy + oj;
    int vz = cz + ok;

    // in-bounds mask (unsigned trick covers <0 and >=256)
    if ((unsigned)vx >= (unsigned)D0 ||
        (unsigned)vy >= (unsigned)D1 ||
        (unsigned)vz >= (unsigned)D2) return;

    float dx = (float)vx - px;
    float dy = (float)vy - py;
    float dz = (float)vz - pz;

    float dist = dist_p[0];
    float dist2 = dx * dx + dy * dy + dz * dz;
    if (dist2 > dist * dist) return;

    float val = paras[3 * N + p];
    float rx  = paras[4 * N + p];
    float rxy = paras[5 * N + p];
    float rxz = paras[6 * N + p];
    float ry  = paras[7 * N + p];
    float ryz = paras[8 * N + p];
    float rz  = paras[9 * N + p];

    float ax = dx * __fdividef(1.0f, rx);
    float ay = dy * __fdividef(1.0f, ry);
    float az = dz * __fdividef(1.0f, rz);
    float q = ax * ax + ay * ay + az * az
            + rxy * dx * dy + rxz * dx * dz + ryz * dy * dz;
    float w = __expf(-0.5f * q);

    float thr = thr_p[0];
    if (w > thr) {
        int flat = (vx * D1 + vy) * D2 + vz;
        atomicAdd(&out[flat], val * w);
    }
}

extern "C" void kernel_launch(void* const* d_in, const int* in_sizes, int n_in,
                              void* d_out, int out_size, void* d_ws, size_t ws_size,
                              hipStream_t stream) {
    const float* paras  = (const float*)d_in[0];
    const float* dist_p = (const float*)d_in[1];
    const float* thr_p  = (const float*)d_in[2];
    float* out = (float*)d_out;

    // Output is re-poisoned (0xAA) before every timed launch; zero it.
    hipMemsetAsync(out, 0, (size_t)out_size * sizeof(float), stream);

    int threads = 256;
    int blocks = (TOTAL_PAIRS + threads - 1) / threads;
    splat_kernel<<<blocks, threads, 0, stream>>>(paras, dist_p, thr_p, out);
}